// Round 1
// 2720.066 us; speedup vs baseline: 1.0268x; 1.0268x over previous
//
#include <hip/hip_runtime.h>
#include <cstdint>
#include <cstddef>

#define B_  2
#define L_  1024
#define DM  1024
#define DI  2048
#define DSN 16
#define DR  64

typedef short          s16x8 __attribute__((ext_vector_type(8)));
typedef float          f32x4 __attribute__((ext_vector_type(4)));
typedef unsigned short u16;
typedef unsigned short u16x4 __attribute__((ext_vector_type(4)));
typedef unsigned int   u32x4 __attribute__((ext_vector_type(4)));

__device__ __forceinline__ u16 f2bf(float f) {
  union { float f; unsigned int u; } v; v.f = f;
  unsigned int u = v.u;
  u += 0x7fffu + ((u >> 16) & 1u);   // round-to-nearest-even
  return (u16)(u >> 16);
}

// DPP cross-lane add: x + dpp_perm(x). VALU-latency, no LDS round-trip.
template <int CTRL>
__device__ __forceinline__ float dpp_add(float x) {
  union { float f; int i; } u, r;
  u.f = x;
  r.i = __builtin_amdgcn_update_dpp(0, u.i, CTRL, 0xf, 0xf, false);
  return x + r.f;
}

// ---------------- fp32 -> bf16 convert (vectorized, grid covers n/4) -------
__global__ __launch_bounds__(256) void k_cvt_bf16(const float* __restrict__ in,
                                                  u16* __restrict__ out, int n4) {
  int i = blockIdx.x * 256 + threadIdx.x;
  if (i < n4) {
    f32x4 v = *(const f32x4*)(in + (size_t)i * 4);
    u16x4 o;
    o[0] = f2bf(v[0]); o[1] = f2bf(v[1]); o[2] = f2bf(v[2]); o[3] = f2bf(v[3]);
    *(u16x4*)(out + (size_t)i * 4) = o;
  }
}

// ---------------- embedding gather: one block per (b,l) row ----------------
__global__ __launch_bounds__(256) void k_gather(const int* __restrict__ tok,
                                                const float* __restrict__ emb,
                                                float* __restrict__ h) {
  int row = blockIdx.x;
  int t = tok[row];
  f32x4 v = ((const f32x4*)(emb + (size_t)t * DM))[threadIdx.x];
  ((f32x4*)(h + (size_t)row * DM))[threadIdx.x] = v;
}

// ---------------- rmsnorm (fp32 in) -> bf16 out, one block per row ---------
__global__ __launch_bounds__(256) void k_rmsnorm_bf16(const float* __restrict__ x,
                                                      const float* __restrict__ w,
                                                      u16* __restrict__ out) {
  int row = blockIdx.x;
  int tid = threadIdx.x;
  f32x4 v = ((const f32x4*)(x + (size_t)row * DM))[tid];
  float ss = v[0]*v[0] + v[1]*v[1] + v[2]*v[2] + v[3]*v[3];
  #pragma unroll
  for (int m = 1; m < 64; m <<= 1) ss += __shfl_xor(ss, m);
  __shared__ float red[4];
  if ((tid & 63) == 0) red[tid >> 6] = ss;
  __syncthreads();
  float tot = red[0] + red[1] + red[2] + red[3];
  float sc = rsqrtf(tot * (1.0f / DM) + 1e-5f);
  f32x4 wv = ((const f32x4*)w)[tid];
  u16x4 o;
  o[0] = f2bf(v[0]*sc*wv[0]); o[1] = f2bf(v[1]*sc*wv[1]);
  o[2] = f2bf(v[2]*sc*wv[2]); o[3] = f2bf(v[3]*sc*wv[3]);
  ((u16x4*)(out + (size_t)row * DM))[tid] = o;
}

// ---------------- depthwise causal conv(4) + silu; fp32 + bf16 outputs -----
__global__ __launch_bounds__(256) void k_conv_silu(const float* __restrict__ xz,
                                                   const float* __restrict__ cw,
                                                   const float* __restrict__ cb,
                                                   float* __restrict__ xcf,
                                                   u16* __restrict__ xcbf) {
  int e = blockIdx.x * 256 + threadIdx.x;      // over B*L*DI
  int c = e & (DI - 1);
  int row = e >> 11;                            // b*L + l
  int l = row & (L_ - 1);
  const float* base = xz + (size_t)row * (2 * DI) + c;
  float acc = cb[c];
  float w0 = cw[c*4+0], w1 = cw[c*4+1], w2 = cw[c*4+2], w3 = cw[c*4+3];
  if (l >= 3) acc += base[-3 * (2 * DI)] * w0;
  if (l >= 2) acc += base[-2 * (2 * DI)] * w1;
  if (l >= 1) acc += base[-1 * (2 * DI)] * w2;
  acc += base[0] * w3;
  float s = acc / (1.f + __expf(-acc));
  xcf[e] = s;
  xcbf[e] = f2bf(s);
}

// ---------------- selective scan, fused D-skip + silu(z) gate, bf16 out ----
// block = 16 channels x 16 states; grid = B * (DI/16).
// Latency-focused design (1 wave/SIMD, nothing to hide behind):
//  - y-reduction over the 16 states via DPP butterfly (quad_perm xor1/xor2,
//    row_half_mirror, row_mirror) -> pure VALU, no serial ds_swizzle+waitcnt.
//  - LDS tiles transposed to [feature][time] (+4 pad) -> one broadcast
//    ds_read_b128 covers 4 timesteps per operand.
//  - async-STAGE split: next tile's global loads issued before the compute
//    phase, written to LDS after the barrier (HBM latency hidden under the
//    64-step compute).
__global__ __launch_bounds__(256) void k_scan(const float* __restrict__ dt,
                                              const float* __restrict__ xcf,
                                              const float* __restrict__ xdbl,
                                              const float* __restrict__ xz,
                                              const float* __restrict__ A_log,
                                              const float* __restrict__ Dsk,
                                              u16* __restrict__ ybf) {
  const int b  = blockIdx.x >> 7;
  const int c0 = (blockIdx.x & 127) << 4;
  const int tid = threadIdx.x;
  const int cl = tid >> 4, s = tid & 15;
  const int c  = c0 + cl;
  const float a2  = -__expf(A_log[c * DSN + s]) * 1.4426950408889634f; // A*log2(e)
  const float dsk = Dsk[c];

  // [feature][time] tiles, 64 timesteps, +4 pad keeps rows 16B-aligned and
  // spreads banks (2-way worst case = free).
  __shared__ __align__(16) float sdt[16][68], sxc[16][68], szg[16][68],
                                 sB[16][68], sC[16][68];

  float hs = 0.f;
  const size_t rowbase = (size_t)b * L_;

  // this thread stages elements (tt = cl + 16k, feature = s) of each tile
  float gdt[4], gxc[4], gz[4], gB[4], gC[4];
  auto stage_load = [&](int t0) {
    #pragma unroll
    for (int k = 0; k < 4; ++k) {
      size_t r = rowbase + t0 + cl + 16 * k;
      gdt[k] = dt  [r * DI + c0 + s];
      gxc[k] = xcf [r * DI + c0 + s];
      gz[k]  = xz  [r * (2 * DI) + DI + c0 + s];
      gB[k]  = xdbl[r * 96 + 64 + s];
      gC[k]  = xdbl[r * 96 + 80 + s];
    }
  };
  auto stage_write = [&]() {
    #pragma unroll
    for (int k = 0; k < 4; ++k) {
      int tt = cl + 16 * k;
      sdt[s][tt] = gdt[k];
      sxc[s][tt] = gxc[k];
      szg[s][tt] = gz[k];
      sB [s][tt] = gB[k];
      sC [s][tt] = gC[k];
    }
  };

  stage_load(0);
  stage_write();
  __syncthreads();

  for (int t0 = 0; t0 < L_; t0 += 64) {
    const bool more = (t0 + 64) < L_;
    if (more) stage_load(t0 + 64);      // in flight across the compute phase
    #pragma unroll
    for (int q = 0; q < 16; ++q) {
      f32x4 vdt = *(const f32x4*)&sdt[cl][q * 4];
      f32x4 vxc = *(const f32x4*)&sxc[cl][q * 4];
      f32x4 vB  = *(const f32x4*)&sB [s][q * 4];
      f32x4 vC  = *(const f32x4*)&sC [s][q * 4];
      #pragma unroll
      for (int j = 0; j < 4; ++j) {
        float dtv = vdt[j], xv = vxc[j];
        float dA = exp2f(dtv * a2);           // off the serial chain
        hs = dA * hs + dtv * xv * vB[j];      // the only true recurrence
        float yv = hs * vC[j];
        yv = dpp_add<0xB1>(yv);   // quad_perm [1,0,3,2] : xor 1
        yv = dpp_add<0x4E>(yv);   // quad_perm [2,3,0,1] : xor 2
        yv = dpp_add<0x141>(yv);  // row_half_mirror     : combine quads
        yv = dpp_add<0x140>(yv);  // row_mirror          : combine halves
        if (s == 0) {
          float zv = szg[cl][q * 4 + j];
          float yo = (yv + xv * dsk) * (zv / (1.f + __expf(-zv)));
          ybf[(rowbase + t0 + q * 4 + j) * DI + c] = f2bf(yo);
        }
      }
    }
    __syncthreads();
    if (more) stage_write();
    __syncthreads();
  }
}

// ---------------- bf16 MFMA NT-GEMM: C(MxN) = A(MxK) . W(NxK)^T ------------
// EPI: 0 = plain fp32 store; 1 = +=residual(C preloaded); 2 = softplus(v+bias[n]);
//      3 = plain store + bf16 aux for n<DR (x_proj -> dtr)
template <int WM, int WN, int EPI>
__global__ __launch_bounds__(256) void k_gemm(const u16* __restrict__ A,
                                              const u16* __restrict__ W,
                                              float* __restrict__ C,
                                              u16* __restrict__ aux,
                                              const float* __restrict__ bias,
                                              int M, int N, int K) {
  constexpr int BM = 32 * WM, BN = 32 * WN, BK = 32;
  __shared__ __align__(16) u16 As[BM * BK];
  __shared__ __align__(16) u16 Bs[BN * BK];
  const int tid = threadIdx.x;
  const int m0 = blockIdx.y * BM, n0 = blockIdx.x * BN;
  const int wave = tid >> 6, lane = tid & 63;
  const int wm = wave & 1, wn = wave >> 1;
  const int l15 = lane & 15, quad = lane >> 4;

  f32x4 acc[WM][WN];
  #pragma unroll
  for (int i = 0; i < WM; ++i)
    #pragma unroll
    for (int j = 0; j < WN; ++j)
      acc[i][j] = f32x4{0.f, 0.f, 0.f, 0.f};

  for (int k0 = 0; k0 < K; k0 += BK) {
    for (int i = tid; i < BM * 4; i += 256) {
      int r = i >> 2, cc = i & 3;
      *(u32x4*)(As + r * BK + cc * 8) =
          *(const u32x4*)(A + (size_t)(m0 + r) * K + k0 + cc * 8);
    }
    for (int i = tid; i < BN * 4; i += 256) {
      int r = i >> 2, cc = i & 3;
      *(u32x4*)(Bs + r * BK + cc * 8) =
          *(const u32x4*)(W + (size_t)(n0 + r) * K + k0 + cc * 8);
    }
    __syncthreads();
    s16x8 af[WM], bfv[WN];
    #pragma unroll
    for (int i = 0; i < WM; ++i)
      af[i] = *(const s16x8*)(As + (wm * WM * 16 + i * 16 + l15) * BK + quad * 8);
    #pragma unroll
    for (int j = 0; j < WN; ++j)
      bfv[j] = *(const s16x8*)(Bs + (wn * WN * 16 + j * 16 + l15) * BK + quad * 8);
    #pragma unroll
    for (int i = 0; i < WM; ++i)
      #pragma unroll
      for (int j = 0; j < WN; ++j)
        acc[i][j] = __builtin_amdgcn_mfma_f32_16x16x32_bf16(af[i], bfv[j], acc[i][j], 0, 0, 0);
    __syncthreads();
  }

  #pragma unroll
  for (int i = 0; i < WM; ++i) {
    #pragma unroll
    for (int j = 0; j < WN; ++j) {
      int mb = m0 + wm * WM * 16 + i * 16 + quad * 4;
      int nb = n0 + wn * WN * 16 + j * 16 + l15;
      #pragma unroll
      for (int r = 0; r < 4; ++r) {
        size_t idx = (size_t)(mb + r) * N + nb;
        float v = acc[i][j][r];
        if constexpr (EPI == 1) v += C[idx];
        if constexpr (EPI == 2) {
          v += bias[nb];
          v = (v > 20.f) ? v : log1pf(__expf(v));
        }
        C[idx] = v;
        if constexpr (EPI == 3) {
          if (nb < DR) aux[(size_t)(mb + r) * DR + nb] = f2bf(v);
        }
      }
    }
  }
}

// ---------------------------------------------------------------------------
extern "C" void kernel_launch(void* const* d_in, const int* in_sizes, int n_in,
                              void* d_out, int out_size, void* d_ws, size_t ws_size,
                              hipStream_t stream) {
  const int*   tokens = (const int*)d_in[0];
  const float* embed  = (const float*)d_in[1];
  const float* norm_w = (const float*)d_in[2];
  const float* in_w   = (const float*)d_in[3];
  const float* conv_w = (const float*)d_in[4];
  const float* conv_b = (const float*)d_in[5];
  const float* xp_w   = (const float*)d_in[6];
  const float* dt_w   = (const float*)d_in[7];
  const float* dt_b   = (const float*)d_in[8];
  const float* A_log  = (const float*)d_in[9];
  const float* D_skip = (const float*)d_in[10];
  const float* out_w  = (const float*)d_in[11];
  const float* fnw    = (const float*)d_in[12];
  float* logits = (float*)d_out;

  char* ws = (char*)d_ws;
  size_t off = 0;
  auto alloc = [&](size_t bytes) -> void* {
    void* p = ws + off;
    off = (off + bytes + 255) & ~(size_t)255;
    return p;
  };
  const size_t R = (size_t)B_ * L_;                 // 2048 rows
  float* h     = (float*)alloc(R * DM * 4);         //  8 MB
  u16*   xbf   = (u16*)  alloc(R * DM * 2);         //  4 MB
  float* xz    = (float*)alloc(R * 2 * DI * 4);     // 32 MB
  float* xcf   = (float*)alloc(R * DI * 4);         // 16 MB
  u16*   xcbf  = (u16*)  alloc(R * DI * 2);         //  8 MB
  float* xdbl  = (float*)alloc(R * 96 * 4);         // .75 MB
  u16*   dtrbf = (u16*)  alloc(R * DR * 2);         // .25 MB
  float* dtv   = (float*)alloc(R * DI * 4);         // 16 MB
  u16*   ybf   = (u16*)  alloc(R * DI * 2);         //  8 MB
  u16*   w_in  = (u16*)  alloc((size_t)2 * DI * DM * 2);  //  8 MB (per-layer, reused)
  u16*   w_out = (u16*)  alloc((size_t)DM * DI * 2);      //  4 MB
  u16*   w_xp  = (u16*)  alloc((size_t)96 * DI * 2);      // .4 MB
  u16*   w_dt  = (u16*)  alloc((size_t)DI * DR * 2);      // .25 MB
  u16*   embbf = (u16*)  alloc(32000ull * DM * 2);        // 62.5 MB
  // total ~169 MB; guard against a smaller-than-expected workspace so an
  // undersized ws shows up as a clean absmax failure, not a container crash.
  if (off > ws_size) return;

  auto cvt = [&](const float* src, u16* dst, size_t n) {
    int n4 = (int)(n / 4);
    k_cvt_bf16<<<(n4 + 255) / 256, 256, 0, stream>>>(src, dst, n4);
  };
  cvt(embed, embbf, 32000ull * DM);

  k_gather<<<(int)R, 256, 0, stream>>>(tokens, embed, h);

  for (int i = 0; i < 4; ++i) {
    cvt(in_w  + (size_t)i * 2 * DI * DM, w_in,  (size_t)2 * DI * DM);
    cvt(out_w + (size_t)i * DM * DI,     w_out, (size_t)DM * DI);
    cvt(xp_w  + (size_t)i * 96 * DI,     w_xp,  (size_t)96 * DI);
    cvt(dt_w  + (size_t)i * DI * DR,     w_dt,  (size_t)DI * DR);

    k_rmsnorm_bf16<<<(int)R, 256, 0, stream>>>(h, norm_w + i * DM, xbf);
    // in_proj: (2048,1024) x (4096,1024)^T -> xz (2048,4096)
    k_gemm<4, 4, 0><<<dim3(2 * DI / 128, (int)R / 128), 256, 0, stream>>>(
        xbf, w_in, xz, nullptr, nullptr, (int)R, 2 * DI, DM);
    k_conv_silu<<<(int)(R * DI) / 256, 256, 0, stream>>>(
        xz, conv_w + i * DI * 4, conv_b + i * DI, xcf, xcbf);
    // x_proj: (2048,2048) x (96,2048)^T -> xdbl (2048,96), aux dtr bf16
    k_gemm<2, 3, 3><<<dim3(1, (int)R / 64), 256, 0, stream>>>(
        xcbf, w_xp, xdbl, dtrbf, nullptr, (int)R, 96, DI);
    // dt_proj: (2048,64) x (2048,64)^T -> softplus(.+dt_b) -> dt (2048,2048)
    k_gemm<4, 4, 2><<<dim3(DI / 128, (int)R / 128), 256, 0, stream>>>(
        dtrbf, w_dt, dtv, nullptr, dt_b + i * DI, (int)R, DI, DR);
    k_scan<<<B_ * (DI / 16), 256, 0, stream>>>(
        dtv, xcf, xdbl, xz, A_log + i * DI * DSN, D_skip + i * DI, ybf);
    // out_proj: (2048,2048) x (1024,2048)^T, residual add in-place into h
    k_gemm<4, 4, 1><<<dim3(DM / 128, (int)R / 128), 256, 0, stream>>>(
        ybf, w_out, h, nullptr, nullptr, (int)R, DM, DI);
  }
  k_rmsnorm_bf16<<<(int)R, 256, 0, stream>>>(h, fnw, xbf);
  // logits: (2048,1024) x (32000,1024)^T -> d_out (2048,32000)
  k_gemm<4, 4, 0><<<dim3(32000 / 128, (int)R / 128), 256, 0, stream>>>(
      xbf, embbf, logits, nullptr, nullptr, (int)R, 32000, DM);
}

// Round 3
// 1655.669 us; speedup vs baseline: 1.6868x; 1.6429x over previous
//
#include <hip/hip_runtime.h>
#include <cstdint>
#include <cstddef>

#define B_  2
#define L_  1024
#define DM  1024
#define DI  2048
#define DSN 16
#define DR  64

typedef short          s16x8 __attribute__((ext_vector_type(8)));
typedef float          f32x4 __attribute__((ext_vector_type(4)));
typedef unsigned short u16;
typedef unsigned short u16x4 __attribute__((ext_vector_type(4)));
typedef unsigned int   u32x4 __attribute__((ext_vector_type(4)));

__device__ __forceinline__ u16 f2bf(float f) {
  union { float f; unsigned int u; } v; v.f = f;
  unsigned int u = v.u;
  u += 0x7fffu + ((u >> 16) & 1u);   // round-to-nearest-even
  return (u16)(u >> 16);
}

// DPP cross-lane add: x + dpp_perm(x). VALU-latency, no LDS round-trip.
template <int CTRL>
__device__ __forceinline__ float dpp_add(float x) {
  union { float f; int i; } u, r;
  u.f = x;
  r.i = __builtin_amdgcn_update_dpp(0, u.i, CTRL, 0xf, 0xf, false);
  return x + r.f;
}

// global -> LDS direct DMA, 16B per lane. LDS dest = wave-uniform base + lane*16;
// global source is per-lane.
#define GLDS(gsrc, ldst)                                                      \
  __builtin_amdgcn_global_load_lds(                                           \
      (const __attribute__((address_space(1))) unsigned int*)(gsrc),          \
      (__attribute__((address_space(3))) unsigned int*)(ldst), 16, 0, 0)

// ---------------- fp32 -> bf16 convert (vectorized, grid covers n/4) -------
__global__ __launch_bounds__(256) void k_cvt_bf16(const float* __restrict__ in,
                                                  u16* __restrict__ out, int n4) {
  int i = blockIdx.x * 256 + threadIdx.x;
  if (i < n4) {
    f32x4 v = *(const f32x4*)(in + (size_t)i * 4);
    u16x4 o;
    o[0] = f2bf(v[0]); o[1] = f2bf(v[1]); o[2] = f2bf(v[2]); o[3] = f2bf(v[3]);
    *(u16x4*)(out + (size_t)i * 4) = o;
  }
}

// ---------------- embedding gather: one block per (b,l) row ----------------
__global__ __launch_bounds__(256) void k_gather(const int* __restrict__ tok,
                                                const float* __restrict__ emb,
                                                float* __restrict__ h) {
  int row = blockIdx.x;
  int t = tok[row];
  f32x4 v = ((const f32x4*)(emb + (size_t)t * DM))[threadIdx.x];
  ((f32x4*)(h + (size_t)row * DM))[threadIdx.x] = v;
}

// ---------------- rmsnorm (fp32 in) -> bf16 out, one block per row ---------
__global__ __launch_bounds__(256) void k_rmsnorm_bf16(const float* __restrict__ x,
                                                      const float* __restrict__ w,
                                                      u16* __restrict__ out) {
  int row = blockIdx.x;
  int tid = threadIdx.x;
  f32x4 v = ((const f32x4*)(x + (size_t)row * DM))[tid];
  float ss = v[0]*v[0] + v[1]*v[1] + v[2]*v[2] + v[3]*v[3];
  #pragma unroll
  for (int m = 1; m < 64; m <<= 1) ss += __shfl_xor(ss, m);
  __shared__ float red[4];
  if ((tid & 63) == 0) red[tid >> 6] = ss;
  __syncthreads();
  float tot = red[0] + red[1] + red[2] + red[3];
  float sc = rsqrtf(tot * (1.0f / DM) + 1e-5f);
  f32x4 wv = ((const f32x4*)w)[tid];
  u16x4 o;
  o[0] = f2bf(v[0]*sc*wv[0]); o[1] = f2bf(v[1]*sc*wv[1]);
  o[2] = f2bf(v[2]*sc*wv[2]); o[3] = f2bf(v[3]*sc*wv[3]);
  ((u16x4*)(out + (size_t)row * DM))[tid] = o;
}

// ---------------- depthwise causal conv(4) + silu; fp32 + bf16 outputs -----
__global__ __launch_bounds__(256) void k_conv_silu(const float* __restrict__ xz,
                                                   const float* __restrict__ cw,
                                                   const float* __restrict__ cb,
                                                   float* __restrict__ xcf,
                                                   u16* __restrict__ xcbf) {
  int e = blockIdx.x * 256 + threadIdx.x;      // over B*L*DI
  int c = e & (DI - 1);
  int row = e >> 11;                            // b*L + l
  int l = row & (L_ - 1);
  const float* base = xz + (size_t)row * (2 * DI) + c;
  float acc = cb[c];
  float w0 = cw[c*4+0], w1 = cw[c*4+1], w2 = cw[c*4+2], w3 = cw[c*4+3];
  if (l >= 3) acc += base[-3 * (2 * DI)] * w0;
  if (l >= 2) acc += base[-2 * (2 * DI)] * w1;
  if (l >= 1) acc += base[-1 * (2 * DI)] * w2;
  acc += base[0] * w3;
  float s = acc / (1.f + __expf(-acc));
  xcf[e] = s;
  xcbf[e] = f2bf(s);
}

// ---------------- selective scan v3 ----------------------------------------
// block = 16 channels x 16 states; grid = B * (DI/16), 1 wave/SIMD.
// v3: no per-step divergent tail. The DPP butterfly leaves y(t) in ALL lanes;
// lane s keeps step t where t%16==s (cndmask, no branch). Every 16 steps all
// 64 lanes do the z-gate + f2bf + store in parallel (z tile is [time][feat]).
// D-skip folded into the per-step path as one broadcast FMA. 1-deep pipeline
// on the per-q ds_read_b128s hides LDS latency.
__global__ __launch_bounds__(256) void k_scan(const float* __restrict__ dt,
                                              const float* __restrict__ xcf,
                                              const float* __restrict__ xdbl,
                                              const float* __restrict__ xz,
                                              const float* __restrict__ A_log,
                                              const float* __restrict__ Dsk,
                                              u16* __restrict__ ybf) {
  const int b  = blockIdx.x >> 7;
  const int c0 = (blockIdx.x & 127) << 4;
  const int tid = threadIdx.x;
  const int cl = tid >> 4, s = tid & 15;
  const int c  = c0 + cl;
  const float a2  = -__expf(A_log[c * DSN + s]) * 1.4426950408889634f; // A*log2(e)
  const float dsk = Dsk[c];

  // recurrence operands [feature][time] (+4 pad); z gate [time][feat] (+1 pad)
  __shared__ __align__(16) float sdt[16][68], sxc[16][68], sB[16][68], sC[16][68];
  __shared__ float szg[64][17];

  float hs = 0.f, ysel = 0.f;
  const size_t rowbase = (size_t)b * L_;

  float gdt[4], gxc[4], gz[4], gB[4], gC[4];
  auto stage_load = [&](int t0) {
    #pragma unroll
    for (int k = 0; k < 4; ++k) {
      size_t r = rowbase + t0 + cl + 16 * k;
      gdt[k] = dt  [r * DI + c0 + s];
      gxc[k] = xcf [r * DI + c0 + s];
      gz[k]  = xz  [r * (2 * DI) + DI + c0 + s];
      gB[k]  = xdbl[r * 96 + 64 + s];
      gC[k]  = xdbl[r * 96 + 80 + s];
    }
  };
  auto stage_write = [&]() {
    #pragma unroll
    for (int k = 0; k < 4; ++k) {
      int tt = cl + 16 * k;
      sdt[s][tt] = gdt[k];
      sxc[s][tt] = gxc[k];
      sB [s][tt] = gB[k];
      sC [s][tt] = gC[k];
      szg[tt][s] = gz[k];
    }
  };

  stage_load(0);
  stage_write();
  __syncthreads();

  for (int t0 = 0; t0 < L_; t0 += 64) {
    const bool more = (t0 + 64) < L_;
    if (more) stage_load(t0 + 64);      // in flight across the compute phase

    f32x4 vdt = *(const f32x4*)&sdt[cl][0];
    f32x4 vxc = *(const f32x4*)&sxc[cl][0];
    f32x4 vB  = *(const f32x4*)&sB [s][0];
    f32x4 vC  = *(const f32x4*)&sC [s][0];
    #pragma unroll
    for (int q = 0; q < 16; ++q) {
      f32x4 ndt, nxc, nB, nC;
      if (q < 15) {                     // prefetch next q-group (compile-time)
        ndt = *(const f32x4*)&sdt[cl][q * 4 + 4];
        nxc = *(const f32x4*)&sxc[cl][q * 4 + 4];
        nB  = *(const f32x4*)&sB [s][q * 4 + 4];
        nC  = *(const f32x4*)&sC [s][q * 4 + 4];
      }
      #pragma unroll
      for (int j = 0; j < 4; ++j) {
        float dtvj = vdt[j], xvj = vxc[j];
        float dA = exp2f(dtvj * a2);
        hs = dA * hs + (dtvj * xvj) * vB[j];
        float yv = hs * vC[j];
        yv = dpp_add<0xB1>(yv);   // quad_perm xor1
        yv = dpp_add<0x4E>(yv);   // quad_perm xor2
        yv = dpp_add<0x141>(yv);  // row_half_mirror -> 8-lane sums
        yv = dpp_add<0x140>(yv);  // row_mirror      -> 16-lane sums (all lanes)
        yv += xvj * dsk;          // D-skip, broadcast FMA
        const int sidx = ((q & 3) << 2) | j;
        ysel = (sidx == s) ? yv : ysel;   // keep my step, no branch
      }
      if ((q & 3) == 3) {                 // 16 steps done: all-lane epilogue
        int tt = ((q >> 2) << 4) + s;     // this lane's timestep in the tile
        float zv = szg[tt][cl];
        float sig = __builtin_amdgcn_rcpf(1.f + __expf(-zv));
        float yo = ysel * (zv * sig);
        ybf[(rowbase + t0 + tt) * DI + c] = f2bf(yo);
      }
      if (q < 15) { vdt = ndt; vxc = nxc; vB = nB; vC = nC; }
    }
    __syncthreads();
    if (more) stage_write();
    __syncthreads();
  }
}

// ---------------- bf16 MFMA NT-GEMM: C(MxN) = A(MxK) . W(NxK)^T ------------
// Round-1 verified fragment/epilogue layout; staging now via global_load_lds
// width-16 (linear LDS dest, per-lane global src — m97 structure). No LDS
// swizzle: T2 is null at 2-phase structures (regime gate) and the 16B-slot
// space at BK=32 is only 2 bits wide anyway. T1 bijective XCD block swizzle
// for L2 locality on the HBM-heavy logits GEMM.
// EPI: 0 = plain fp32 store; 1 = +=residual(C preloaded); 2 = softplus(v+bias[n]);
//      3 = plain store + bf16 aux for n<DR (x_proj -> dtr)
template <int WM, int WN, int EPI>
__global__ __launch_bounds__(256) void k_gemm(const u16* __restrict__ A,
                                              const u16* __restrict__ W,
                                              float* __restrict__ C,
                                              u16* __restrict__ aux,
                                              const float* __restrict__ bias,
                                              int M, int N, int K) {
  constexpr int BM = 32 * WM, BN = 32 * WN, BK = 32;
  __shared__ __align__(16) u16 As[BM * BK];
  __shared__ __align__(16) u16 Bs[BN * BK];
  const int tid = threadIdx.x;

  // T1: bijective XCD-aware remap of the flattened block id (m204 variant)
  const int gx = gridDim.x;
  const int nwg = gx * gridDim.y;
  const int lin = blockIdx.y * gx + blockIdx.x;
  const int q8 = nwg >> 3, r8 = nwg & 7;
  const int xcd = lin & 7, loc = lin >> 3;
  const int swz = (xcd < r8 ? xcd * (q8 + 1) : r8 * (q8 + 1) + (xcd - r8) * q8) + loc;
  const int m0 = (swz / gx) * BM, n0 = (swz % gx) * BN;

  const int wave = tid >> 6, lane = tid & 63;
  const int wm = wave & 1, wn = wave >> 1;
  const int l15 = lane & 15, quad = lane >> 4;
  const int sr = lane >> 2, scc = lane & 3;   // staging row/16B-slot in chunk

  f32x4 acc[WM][WN];
  #pragma unroll
  for (int i = 0; i < WM; ++i)
    #pragma unroll
    for (int j = 0; j < WN; ++j)
      acc[i][j] = f32x4{0.f, 0.f, 0.f, 0.f};

  constexpr int NA = BM / 16;   // 1KB chunks (16 rows x 32 cols x 2B)
  constexpr int NB = BN / 16;

  for (int k0 = 0; k0 < K; k0 += BK) {
    // GLDS chunk mapping: lane l -> LDS element (l>>2)*32 + (l&3)*8, i.e.
    // the same [row][col] layout the fragment reads use.
    for (int ch = wave; ch < NA; ch += 4) {
      int r = (ch << 4) + sr;
      GLDS(A + (size_t)(m0 + r) * K + k0 + (scc << 3), As + (ch << 9));
    }
    for (int ch = wave; ch < NB; ch += 4) {
      int r = (ch << 4) + sr;
      GLDS(W + (size_t)(n0 + r) * K + k0 + (scc << 3), Bs + (ch << 9));
    }
    __syncthreads();   // drains vmcnt (incl. global_load_lds) before reads
    s16x8 af[WM], bfv[WN];
    #pragma unroll
    for (int i = 0; i < WM; ++i)
      af[i] = *(const s16x8*)(As + (wm * WM * 16 + i * 16 + l15) * BK + quad * 8);
    #pragma unroll
    for (int j = 0; j < WN; ++j)
      bfv[j] = *(const s16x8*)(Bs + (wn * WN * 16 + j * 16 + l15) * BK + quad * 8);
    #pragma unroll
    for (int i = 0; i < WM; ++i)
      #pragma unroll
      for (int j = 0; j < WN; ++j)
        acc[i][j] = __builtin_amdgcn_mfma_f32_16x16x32_bf16(af[i], bfv[j], acc[i][j], 0, 0, 0);
    __syncthreads();
  }

  #pragma unroll
  for (int i = 0; i < WM; ++i) {
    #pragma unroll
    for (int j = 0; j < WN; ++j) {
      int mb = m0 + wm * WM * 16 + i * 16 + quad * 4;
      int nb = n0 + wn * WN * 16 + j * 16 + l15;
      #pragma unroll
      for (int r = 0; r < 4; ++r) {
        size_t idx = (size_t)(mb + r) * N + nb;
        float v = acc[i][j][r];
        if constexpr (EPI == 1) v += C[idx];
        if constexpr (EPI == 2) {
          v += bias[nb];
          v = (v > 20.f) ? v : log1pf(__expf(v));
        }
        C[idx] = v;
        if constexpr (EPI == 3) {
          if (nb < DR) aux[(size_t)(mb + r) * DR + nb] = f2bf(v);
        }
      }
    }
  }
}

// ---------------------------------------------------------------------------
extern "C" void kernel_launch(void* const* d_in, const int* in_sizes, int n_in,
                              void* d_out, int out_size, void* d_ws, size_t ws_size,
                              hipStream_t stream) {
  const int*   tokens = (const int*)d_in[0];
  const float* embed  = (const float*)d_in[1];
  const float* norm_w = (const float*)d_in[2];
  const float* in_w   = (const float*)d_in[3];
  const float* conv_w = (const float*)d_in[4];
  const float* conv_b = (const float*)d_in[5];
  const float* xp_w   = (const float*)d_in[6];
  const float* dt_w   = (const float*)d_in[7];
  const float* dt_b   = (const float*)d_in[8];
  const float* A_log  = (const float*)d_in[9];
  const float* D_skip = (const float*)d_in[10];
  const float* out_w  = (const float*)d_in[11];
  const float* fnw    = (const float*)d_in[12];
  float* logits = (float*)d_out;

  char* ws = (char*)d_ws;
  size_t off = 0;
  auto alloc = [&](size_t bytes) -> void* {
    void* p = ws + off;
    off = (off + bytes + 255) & ~(size_t)255;
    return p;
  };
  const size_t R = (size_t)B_ * L_;                 // 2048 rows
  float* h     = (float*)alloc(R * DM * 4);         //  8 MB
  u16*   xbf   = (u16*)  alloc(R * DM * 2);         //  4 MB
  float* xz    = (float*)alloc(R * 2 * DI * 4);     // 32 MB
  float* xcf   = (float*)alloc(R * DI * 4);         // 16 MB
  u16*   xcbf  = (u16*)  alloc(R * DI * 2);         //  8 MB
  float* xdbl  = (float*)alloc(R * 96 * 4);         // .75 MB
  u16*   dtrbf = (u16*)  alloc(R * DR * 2);         // .25 MB
  float* dtv   = (float*)alloc(R * DI * 4);         // 16 MB
  u16*   ybf   = (u16*)  alloc(R * DI * 2);         //  8 MB
  u16*   w_in  = (u16*)  alloc((size_t)2 * DI * DM * 2);  //  8 MB (per-layer, reused)
  u16*   w_out = (u16*)  alloc((size_t)DM * DI * 2);      //  4 MB
  u16*   w_xp  = (u16*)  alloc((size_t)96 * DI * 2);      // .4 MB
  u16*   w_dt  = (u16*)  alloc((size_t)DI * DR * 2);      // .25 MB
  u16*   embbf = (u16*)  alloc(32000ull * DM * 2);        // 62.5 MB
  // total ~169 MB; guard against a smaller-than-expected workspace so an
  // undersized ws shows up as a clean absmax failure, not a container crash.
  if (off > ws_size) return;

  auto cvt = [&](const float* src, u16* dst, size_t n) {
    int n4 = (int)(n / 4);
    k_cvt_bf16<<<(n4 + 255) / 256, 256, 0, stream>>>(src, dst, n4);
  };
  cvt(embed, embbf, 32000ull * DM);

  k_gather<<<(int)R, 256, 0, stream>>>(tokens, embed, h);

  for (int i = 0; i < 4; ++i) {
    cvt(in_w  + (size_t)i * 2 * DI * DM, w_in,  (size_t)2 * DI * DM);
    cvt(out_w + (size_t)i * DM * DI,     w_out, (size_t)DM * DI);
    cvt(xp_w  + (size_t)i * 96 * DI,     w_xp,  (size_t)96 * DI);
    cvt(dt_w  + (size_t)i * DI * DR,     w_dt,  (size_t)DI * DR);

    k_rmsnorm_bf16<<<(int)R, 256, 0, stream>>>(h, norm_w + i * DM, xbf);
    // in_proj: (2048,1024) x (4096,1024)^T -> xz (2048,4096)
    k_gemm<4, 4, 0><<<dim3(2 * DI / 128, (int)R / 128), 256, 0, stream>>>(
        xbf, w_in, xz, nullptr, nullptr, (int)R, 2 * DI, DM);
    k_conv_silu<<<(int)(R * DI) / 256, 256, 0, stream>>>(
        xz, conv_w + i * DI * 4, conv_b + i * DI, xcf, xcbf);
    // x_proj: (2048,2048) x (96,2048)^T -> xdbl (2048,96), aux dtr bf16
    k_gemm<2, 3, 3><<<dim3(1, (int)R / 64), 256, 0, stream>>>(
        xcbf, w_xp, xdbl, dtrbf, nullptr, (int)R, 96, DI);
    // dt_proj: (2048,64) x (2048,64)^T -> softplus(.+dt_b) -> dt (2048,2048)
    k_gemm<4, 4, 2><<<dim3(DI / 128, (int)R / 128), 256, 0, stream>>>(
        dtrbf, w_dt, dtv, nullptr, dt_b + i * DI, (int)R, DI, DR);
    k_scan<<<B_ * (DI / 16), 256, 0, stream>>>(
        dtv, xcf, xdbl, xz, A_log + i * DI * DSN, D_skip + i * DI, ybf);
    // out_proj: (2048,2048) x (1024,2048)^T, residual add in-place into h
    k_gemm<4, 4, 1><<<dim3(DM / 128, (int)R / 128), 256, 0, stream>>>(
        ybf, w_out, h, nullptr, nullptr, (int)R, DM, DI);
  }
  k_rmsnorm_bf16<<<(int)R, 256, 0, stream>>>(h, fnw, xbf);
  // logits: (2048,1024) x (32000,1024)^T -> d_out (2048,32000)
  k_gemm<4, 4, 0><<<dim3(32000 / 128, (int)R / 128), 256, 0, stream>>>(
      xbf, embbf, logits, nullptr, nullptr, (int)R, 32000, DM);
}

// Round 4
// 1451.666 us; speedup vs baseline: 1.9239x; 1.1405x over previous
//
#include <hip/hip_runtime.h>
#include <cstdint>
#include <cstddef>

#define B_  2
#define L_  1024
#define DM  1024
#define DI  2048
#define DSN 16
#define DR  64

typedef short          s16x8 __attribute__((ext_vector_type(8)));
typedef float          f32x4 __attribute__((ext_vector_type(4)));
typedef unsigned short u16;
typedef unsigned short u16x4 __attribute__((ext_vector_type(4)));
typedef unsigned int   u32x4 __attribute__((ext_vector_type(4)));

__device__ __forceinline__ u16 f2bf(float f) {
  union { float f; unsigned int u; } v; v.f = f;
  unsigned int u = v.u;
  u += 0x7fffu + ((u >> 16) & 1u);   // round-to-nearest-even
  return (u16)(u >> 16);
}

// DPP cross-lane add: x + dpp_perm(x). VALU-latency, no LDS round-trip.
template <int CTRL>
__device__ __forceinline__ float dpp_add(float x) {
  union { float f; int i; } u, r;
  u.f = x;
  r.i = __builtin_amdgcn_update_dpp(0, u.i, CTRL, 0xf, 0xf, false);
  return x + r.f;
}

// global -> LDS direct DMA, 16B per lane. LDS dest = wave-uniform base + lane*16;
// global source is per-lane.
#define GLDS(gsrc, ldst)                                                      \
  __builtin_amdgcn_global_load_lds(                                           \
      (const __attribute__((address_space(1))) unsigned int*)(gsrc),          \
      (__attribute__((address_space(3))) unsigned int*)(ldst), 16, 0, 0)

// ---------------- fp32 -> bf16 convert (vectorized, grid covers n/4) -------
__global__ __launch_bounds__(256) void k_cvt_bf16(const float* __restrict__ in,
                                                  u16* __restrict__ out, int n4) {
  int i = blockIdx.x * 256 + threadIdx.x;
  if (i < n4) {
    f32x4 v = *(const f32x4*)(in + (size_t)i * 4);
    u16x4 o;
    o[0] = f2bf(v[0]); o[1] = f2bf(v[1]); o[2] = f2bf(v[2]); o[3] = f2bf(v[3]);
    *(u16x4*)(out + (size_t)i * 4) = o;
  }
}

// ---------------- embedding gather: one block per (b,l) row ----------------
__global__ __launch_bounds__(256) void k_gather(const int* __restrict__ tok,
                                                const float* __restrict__ emb,
                                                float* __restrict__ h) {
  int row = blockIdx.x;
  int t = tok[row];
  f32x4 v = ((const f32x4*)(emb + (size_t)t * DM))[threadIdx.x];
  ((f32x4*)(h + (size_t)row * DM))[threadIdx.x] = v;
}

// ---------------- rmsnorm (fp32 in) -> bf16 out, one block per row ---------
__global__ __launch_bounds__(256) void k_rmsnorm_bf16(const float* __restrict__ x,
                                                      const float* __restrict__ w,
                                                      u16* __restrict__ out) {
  int row = blockIdx.x;
  int tid = threadIdx.x;
  f32x4 v = ((const f32x4*)(x + (size_t)row * DM))[tid];
  float ss = v[0]*v[0] + v[1]*v[1] + v[2]*v[2] + v[3]*v[3];
  #pragma unroll
  for (int m = 1; m < 64; m <<= 1) ss += __shfl_xor(ss, m);
  __shared__ float red[4];
  if ((tid & 63) == 0) red[tid >> 6] = ss;
  __syncthreads();
  float tot = red[0] + red[1] + red[2] + red[3];
  float sc = rsqrtf(tot * (1.0f / DM) + 1e-5f);
  f32x4 wv = ((const f32x4*)w)[tid];
  u16x4 o;
  o[0] = f2bf(v[0]*sc*wv[0]); o[1] = f2bf(v[1]*sc*wv[1]);
  o[2] = f2bf(v[2]*sc*wv[2]); o[3] = f2bf(v[3]*sc*wv[3]);
  ((u16x4*)(out + (size_t)row * DM))[tid] = o;
}

// ---------------- depthwise causal conv(4) + silu; fp32 + bf16 outputs -----
__global__ __launch_bounds__(256) void k_conv_silu(const float* __restrict__ xz,
                                                   const float* __restrict__ cw,
                                                   const float* __restrict__ cb,
                                                   float* __restrict__ xcf,
                                                   u16* __restrict__ xcbf) {
  int e = blockIdx.x * 256 + threadIdx.x;      // over B*L*DI
  int c = e & (DI - 1);
  int row = e >> 11;                            // b*L + l
  int l = row & (L_ - 1);
  const float* base = xz + (size_t)row * (2 * DI) + c;
  float acc = cb[c];
  float w0 = cw[c*4+0], w1 = cw[c*4+1], w2 = cw[c*4+2], w3 = cw[c*4+3];
  if (l >= 3) acc += base[-3 * (2 * DI)] * w0;
  if (l >= 2) acc += base[-2 * (2 * DI)] * w1;
  if (l >= 1) acc += base[-1 * (2 * DI)] * w2;
  acc += base[0] * w3;
  float s = acc / (1.f + __expf(-acc));
  xcf[e] = s;
  xcbf[e] = f2bf(s);
}

// ---------------- selective scan v4 ----------------------------------------
// block = 16 channels x 16 states; grid = B * (DI/16), 1 wave/SIMD.
// v4 = v3 + 2-deep register prefetch of q-groups (hides ~120cy LDS latency
// fully; 1 wave/SIMD has no TLP to hide it otherwise).
__global__ __launch_bounds__(256) void k_scan(const float* __restrict__ dt,
                                              const float* __restrict__ xcf,
                                              const float* __restrict__ xdbl,
                                              const float* __restrict__ xz,
                                              const float* __restrict__ A_log,
                                              const float* __restrict__ Dsk,
                                              u16* __restrict__ ybf) {
  const int b  = blockIdx.x >> 7;
  const int c0 = (blockIdx.x & 127) << 4;
  const int tid = threadIdx.x;
  const int cl = tid >> 4, s = tid & 15;
  const int c  = c0 + cl;
  const float a2  = -__expf(A_log[c * DSN + s]) * 1.4426950408889634f; // A*log2(e)
  const float dsk = Dsk[c];

  // recurrence operands [feature][time] (+4 pad); z gate [time][feat] (+1 pad)
  __shared__ __align__(16) float sdt[16][68], sxc[16][68], sB[16][68], sC[16][68];
  __shared__ float szg[64][17];

  float hs = 0.f, ysel = 0.f;
  const size_t rowbase = (size_t)b * L_;

  float gdt[4], gxc[4], gz[4], gB[4], gC[4];
  auto stage_load = [&](int t0) {
    #pragma unroll
    for (int k = 0; k < 4; ++k) {
      size_t r = rowbase + t0 + cl + 16 * k;
      gdt[k] = dt  [r * DI + c0 + s];
      gxc[k] = xcf [r * DI + c0 + s];
      gz[k]  = xz  [r * (2 * DI) + DI + c0 + s];
      gB[k]  = xdbl[r * 96 + 64 + s];
      gC[k]  = xdbl[r * 96 + 80 + s];
    }
  };
  auto stage_write = [&]() {
    #pragma unroll
    for (int k = 0; k < 4; ++k) {
      int tt = cl + 16 * k;
      sdt[s][tt] = gdt[k];
      sxc[s][tt] = gxc[k];
      sB [s][tt] = gB[k];
      sC [s][tt] = gC[k];
      szg[tt][s] = gz[k];
    }
  };

  stage_load(0);
  stage_write();
  __syncthreads();

  for (int t0 = 0; t0 < L_; t0 += 64) {
    const bool more = (t0 + 64) < L_;
    if (more) stage_load(t0 + 64);      // in flight across the compute phase

    // 2-deep q-group pipeline; indices compile-time under full unroll.
    f32x4 pdt[2], pxc[2], pB[2], pC[2];
    pdt[0] = *(const f32x4*)&sdt[cl][0]; pdt[1] = *(const f32x4*)&sdt[cl][4];
    pxc[0] = *(const f32x4*)&sxc[cl][0]; pxc[1] = *(const f32x4*)&sxc[cl][4];
    pB[0]  = *(const f32x4*)&sB [s][0];  pB[1]  = *(const f32x4*)&sB [s][4];
    pC[0]  = *(const f32x4*)&sC [s][0];  pC[1]  = *(const f32x4*)&sC [s][4];
    #pragma unroll
    for (int q = 0; q < 16; ++q) {
      const int cur = q & 1;
      f32x4 vdt = pdt[cur], vxc = pxc[cur], vB = pB[cur], vC = pC[cur];
      if (q < 14) {                      // refill with group q+2
        pdt[cur] = *(const f32x4*)&sdt[cl][q * 4 + 8];
        pxc[cur] = *(const f32x4*)&sxc[cl][q * 4 + 8];
        pB[cur]  = *(const f32x4*)&sB [s][q * 4 + 8];
        pC[cur]  = *(const f32x4*)&sC [s][q * 4 + 8];
      }
      #pragma unroll
      for (int j = 0; j < 4; ++j) {
        float dtvj = vdt[j], xvj = vxc[j];
        float dA = exp2f(dtvj * a2);
        hs = dA * hs + (dtvj * xvj) * vB[j];
        float yv = hs * vC[j];
        yv = dpp_add<0xB1>(yv);   // quad_perm xor1
        yv = dpp_add<0x4E>(yv);   // quad_perm xor2
        yv = dpp_add<0x141>(yv);  // row_half_mirror -> 8-lane sums
        yv = dpp_add<0x140>(yv);  // row_mirror      -> 16-lane sums (all lanes)
        yv += xvj * dsk;          // D-skip, broadcast FMA
        const int sidx = ((q & 3) << 2) | j;
        ysel = (sidx == s) ? yv : ysel;   // keep my step, no branch
      }
      if ((q & 3) == 3) {                 // 16 steps done: all-lane epilogue
        int tt = ((q >> 2) << 4) + s;     // this lane's timestep in the tile
        float zv = szg[tt][cl];
        float sig = __builtin_amdgcn_rcpf(1.f + __expf(-zv));
        float yo = ysel * (zv * sig);
        ybf[(rowbase + t0 + tt) * DI + c] = f2bf(yo);
      }
    }
    __syncthreads();
    if (more) stage_write();
    __syncthreads();
  }
}

// ---------------- bf16 MFMA NT-GEMM: C(MxN) = A(MxK) . W(NxK)^T ------------
// GLDS width-16 linear staging (m97 structure). T1 bijective XCD chunking
// with M-FASTEST decode: consecutive blocks in an XCD chunk share one
// B-panel (weight reuse in L2) -> kills the 8x overfetch seen in round 3.
// SK>0: split-K over blockIdx.x (no swizzle), plain store into partial[kb].
// EPI: 0 = plain fp32 store; 1 = +=residual(C preloaded); 2 = softplus(v+bias[n]);
//      3 = plain store + bf16 aux for n<DR (x_proj -> dtr)
template <int WM, int WN, int EPI, int SK>
__global__ __launch_bounds__(256) void k_gemm(const u16* __restrict__ A,
                                              const u16* __restrict__ W,
                                              float* __restrict__ C,
                                              u16* __restrict__ aux,
                                              const float* __restrict__ bias,
                                              int M, int N, int K) {
  constexpr int BM = 32 * WM, BN = 32 * WN, BK = 32;
  __shared__ __align__(16) u16 As[BM * BK];
  __shared__ __align__(16) u16 Bs[BN * BK];
  const int tid = threadIdx.x;

  int m0, n0, kb = 0;
  if constexpr (SK > 0) {
    kb = blockIdx.x;                  // K-split index; no swizzle
    m0 = blockIdx.y * BM;
    n0 = 0;
  } else {
    // T1: bijective XCD-aware remap, m-fastest decode for B-panel reuse
    const int gx = gridDim.x, gy = gridDim.y;
    const int nwg = gx * gy;
    const int lin = blockIdx.y * gx + blockIdx.x;
    const int q8 = nwg >> 3, r8 = nwg & 7;
    const int xcd = lin & 7, loc = lin >> 3;
    const int swz = (xcd < r8 ? xcd * (q8 + 1) : r8 * (q8 + 1) + (xcd - r8) * q8) + loc;
    m0 = (swz % gy) * BM;
    n0 = (swz / gy) * BN;
  }

  const int wave = tid >> 6, lane = tid & 63;
  const int wm = wave & 1, wn = wave >> 1;
  const int l15 = lane & 15, quad = lane >> 4;
  const int sr = lane >> 2, scc = lane & 3;   // staging row/16B-slot in chunk

  f32x4 acc[WM][WN];
  #pragma unroll
  for (int i = 0; i < WM; ++i)
    #pragma unroll
    for (int j = 0; j < WN; ++j)
      acc[i][j] = f32x4{0.f, 0.f, 0.f, 0.f};

  constexpr int NA = BM / 16;   // 1KB chunks (16 rows x 32 cols x 2B)
  constexpr int NB = BN / 16;

  const int kbeg = (SK > 0) ? kb * (K / (SK > 0 ? SK : 1)) : 0;
  const int kend = (SK > 0) ? kbeg + K / (SK > 0 ? SK : 1) : K;

  for (int k0 = kbeg; k0 < kend; k0 += BK) {
    // GLDS chunk mapping: lane l -> LDS element (l>>2)*32 + (l&3)*8, i.e.
    // the same [row][col] layout the fragment reads use.
    for (int ch = wave; ch < NA; ch += 4) {
      int r = (ch << 4) + sr;
      GLDS(A + (size_t)(m0 + r) * K + k0 + (scc << 3), As + (ch << 9));
    }
    for (int ch = wave; ch < NB; ch += 4) {
      int r = (ch << 4) + sr;
      GLDS(W + (size_t)(n0 + r) * K + k0 + (scc << 3), Bs + (ch << 9));
    }
    __syncthreads();   // drains vmcnt (incl. global_load_lds) before reads
    s16x8 af[WM], bfv[WN];
    #pragma unroll
    for (int i = 0; i < WM; ++i)
      af[i] = *(const s16x8*)(As + (wm * WM * 16 + i * 16 + l15) * BK + quad * 8);
    #pragma unroll
    for (int j = 0; j < WN; ++j)
      bfv[j] = *(const s16x8*)(Bs + (wn * WN * 16 + j * 16 + l15) * BK + quad * 8);
    #pragma unroll
    for (int i = 0; i < WM; ++i)
      #pragma unroll
      for (int j = 0; j < WN; ++j)
        acc[i][j] = __builtin_amdgcn_mfma_f32_16x16x32_bf16(af[i], bfv[j], acc[i][j], 0, 0, 0);
    __syncthreads();
  }

  float* Cb = C + ((SK > 0) ? (size_t)kb * M * N : (size_t)0);
  #pragma unroll
  for (int i = 0; i < WM; ++i) {
    #pragma unroll
    for (int j = 0; j < WN; ++j) {
      int mb = m0 + wm * WM * 16 + i * 16 + quad * 4;
      int nb = n0 + wn * WN * 16 + j * 16 + l15;
      #pragma unroll
      for (int r = 0; r < 4; ++r) {
        size_t idx = (size_t)(mb + r) * N + nb;
        float v = acc[i][j][r];
        if constexpr (EPI == 1) v += Cb[idx];
        if constexpr (EPI == 2) {
          v += bias[nb];
          v = (v > 20.f) ? v : log1pf(__expf(v));
        }
        Cb[idx] = v;
        if constexpr (EPI == 3) {
          if (nb < DR) aux[(size_t)(mb + r) * DR + nb] = f2bf(v);
        }
      }
    }
  }
}

// ---------------- x_proj split-K reduce: sum 8 partials, emit fp32 + bf16 --
__global__ __launch_bounds__(256) void k_xp_reduce(const float* __restrict__ part,
                                                   float* __restrict__ xdbl,
                                                   u16* __restrict__ dtr) {
  int e = blockIdx.x * 256 + threadIdx.x;   // over R*24 f32x4 slots (exact)
  int m = e / 24, n4 = e % 24;
  f32x4 acc = *(const f32x4*)(part + (size_t)m * 96 + n4 * 4);
  #pragma unroll
  for (int kb = 1; kb < 8; ++kb) {
    f32x4 p = *(const f32x4*)(part + (size_t)kb * (B_ * L_ * 96) + (size_t)m * 96 + n4 * 4);
    acc[0] += p[0]; acc[1] += p[1]; acc[2] += p[2]; acc[3] += p[3];
  }
  *(f32x4*)(xdbl + (size_t)m * 96 + n4 * 4) = acc;
  if (n4 < 16) {
    u16x4 o;
    o[0] = f2bf(acc[0]); o[1] = f2bf(acc[1]); o[2] = f2bf(acc[2]); o[3] = f2bf(acc[3]);
    *(u16x4*)(dtr + (size_t)m * DR + n4 * 4) = o;
  }
}

// ---------------------------------------------------------------------------
extern "C" void kernel_launch(void* const* d_in, const int* in_sizes, int n_in,
                              void* d_out, int out_size, void* d_ws, size_t ws_size,
                              hipStream_t stream) {
  const int*   tokens = (const int*)d_in[0];
  const float* embed  = (const float*)d_in[1];
  const float* norm_w = (const float*)d_in[2];
  const float* in_w   = (const float*)d_in[3];
  const float* conv_w = (const float*)d_in[4];
  const float* conv_b = (const float*)d_in[5];
  const float* xp_w   = (const float*)d_in[6];
  const float* dt_w   = (const float*)d_in[7];
  const float* dt_b   = (const float*)d_in[8];
  const float* A_log  = (const float*)d_in[9];
  const float* D_skip = (const float*)d_in[10];
  const float* out_w  = (const float*)d_in[11];
  const float* fnw    = (const float*)d_in[12];
  float* logits = (float*)d_out;

  char* ws = (char*)d_ws;
  size_t off = 0;
  auto alloc = [&](size_t bytes) -> void* {
    void* p = ws + off;
    off = (off + bytes + 255) & ~(size_t)255;
    return p;
  };
  const size_t R = (size_t)B_ * L_;                 // 2048 rows
  float* h     = (float*)alloc(R * DM * 4);         //  8 MB
  u16*   xbf   = (u16*)  alloc(R * DM * 2);         //  4 MB
  float* xz    = (float*)alloc(R * 2 * DI * 4);     // 32 MB
  float* xcf   = (float*)alloc(R * DI * 4);         // 16 MB
  u16*   xcbf  = (u16*)  alloc(R * DI * 2);         //  8 MB
  float* xdbl  = (float*)alloc(R * 96 * 4);         // .75 MB
  u16*   dtrbf = (u16*)  alloc(R * DR * 2);         // .25 MB
  float* dtv   = (float*)alloc(R * DI * 4);         // 16 MB
  u16*   ybf   = (u16*)  alloc(R * DI * 2);         //  8 MB
  u16*   w_in  = (u16*)  alloc((size_t)2 * DI * DM * 2);  //  8 MB (per-layer, reused)
  u16*   w_out = (u16*)  alloc((size_t)DM * DI * 2);      //  4 MB
  u16*   w_xp  = (u16*)  alloc((size_t)96 * DI * 2);      // .4 MB
  u16*   w_dt  = (u16*)  alloc((size_t)DI * DR * 2);      // .25 MB
  u16*   embbf = (u16*)  alloc(32000ull * DM * 2);        // 62.5 MB
  float* xp_part = (float*)alloc((size_t)8 * R * 96 * 4); // 6.3 MB (split-K)
  // guard against a smaller-than-expected workspace
  if (off > ws_size) return;

  auto cvt = [&](const float* src, u16* dst, size_t n) {
    int n4 = (int)(n / 4);
    k_cvt_bf16<<<(n4 + 255) / 256, 256, 0, stream>>>(src, dst, n4);
  };
  cvt(embed, embbf, 32000ull * DM);

  k_gather<<<(int)R, 256, 0, stream>>>(tokens, embed, h);

  for (int i = 0; i < 4; ++i) {
    cvt(in_w  + (size_t)i * 2 * DI * DM, w_in,  (size_t)2 * DI * DM);
    cvt(out_w + (size_t)i * DM * DI,     w_out, (size_t)DM * DI);
    cvt(xp_w  + (size_t)i * 96 * DI,     w_xp,  (size_t)96 * DI);
    cvt(dt_w  + (size_t)i * DI * DR,     w_dt,  (size_t)DI * DR);

    k_rmsnorm_bf16<<<(int)R, 256, 0, stream>>>(h, norm_w + i * DM, xbf);
    // in_proj: (2048,1024) x (4096,1024)^T -> xz (2048,4096)
    k_gemm<4, 4, 0, 0><<<dim3(2 * DI / 128, (int)R / 128), 256, 0, stream>>>(
        xbf, w_in, xz, nullptr, nullptr, (int)R, 2 * DI, DM);
    k_conv_silu<<<(int)(R * DI) / 256, 256, 0, stream>>>(
        xz, conv_w + i * DI * 4, conv_b + i * DI, xcf, xcbf);
    // x_proj: (2048,2048) x (96,2048)^T, split-K=8 -> partials, then reduce
    k_gemm<2, 3, 0, 8><<<dim3(8, (int)R / 64), 256, 0, stream>>>(
        xcbf, w_xp, xp_part, nullptr, nullptr, (int)R, 96, DI);
    k_xp_reduce<<<(int)(R * 24) / 256, 256, 0, stream>>>(xp_part, xdbl, dtrbf);
    // dt_proj: (2048,64) x (2048,64)^T -> softplus(.+dt_b) -> dt (2048,2048)
    k_gemm<4, 4, 2, 0><<<dim3(DI / 128, (int)R / 128), 256, 0, stream>>>(
        dtrbf, w_dt, dtv, nullptr, dt_b + i * DI, (int)R, DI, DR);
    k_scan<<<B_ * (DI / 16), 256, 0, stream>>>(
        dtv, xcf, xdbl, xz, A_log + i * DI * DSN, D_skip + i * DI, ybf);
    // out_proj: (2048,2048) x (1024,2048)^T, residual add in-place into h
    k_gemm<4, 4, 1, 0><<<dim3(DM / 128, (int)R / 128), 256, 0, stream>>>(
        ybf, w_out, h, nullptr, nullptr, (int)R, DM, DI);
  }
  k_rmsnorm_bf16<<<(int)R, 256, 0, stream>>>(h, fnw, xbf);
  // logits: (2048,1024) x (32000,1024)^T -> d_out (2048,32000)
  k_gemm<4, 4, 0, 0><<<dim3(32000 / 128, (int)R / 128), 256, 0, stream>>>(
      xbf, embbf, logits, nullptr, nullptr, (int)R, 32000, DM);
}